// Round 13
// baseline (210.547 us; speedup 1.0000x reference)
//
#include <hip/hip_runtime.h>
#include <hip/hip_bf16.h>

// GAT layer: N=4096, F_IN=128, F_OUT=64, HEADS=4.
// R13: best-known (R11) + two targeted changes:
//  - gat_main: single-buffered LDS, 256-col chunks (8 MFMA-steps/barrier,
//    4 barriers total vs R11's 8). LDS 36.6 KB -> 4 blocks/CU = 32 waves/CU.
//  - pack_bits + gat_prep fused into one dispatch (prep = first 512 block ids,
//    pack = rest): HBM-bound pack overlaps compute-bound prep.
// R12 lesson: reg-prefetch dbuf regressed (WRITE +34 MB, occ 62%) — reverted.
// Kernels: gat_pp (fused) -> gat_main -> gat_fin.

#define NN 4096
#define FIN 128
#define FOUT 64
#define NH 4

typedef __attribute__((ext_vector_type(8))) short bf16x8;
typedef __attribute__((ext_vector_type(4))) float f32x4;
typedef __attribute__((ext_vector_type(4))) unsigned int u32x4;

__device__ __forceinline__ unsigned short f32_bf16(float f) {
    unsigned u = __builtin_bit_cast(unsigned, f);
    u += 0x7fffu + ((u >> 16) & 1u);          // round-to-nearest-even
    return (unsigned short)(u >> 16);
}

// ---------------- Kernel 1: fused pack_bits + prep ----------------
// blocks [0,512): prep (rb = id&127, h = id>>7); blocks [512, 4608): pack row.
__global__ __launch_bounds__(256) void gat_pp(
    const float* __restrict__ X, const float* __restrict__ W,
    const float* __restrict__ b, const float* __restrict__ att,
    const int* __restrict__ A, unsigned long long* __restrict__ Abits,
    unsigned short* __restrict__ HbfT, float* __restrict__ Hrow,
    float* __restrict__ s_out, float* __restrict__ d_out,
    float* __restrict__ es_g, float* __restrict__ es2_g,
    float* __restrict__ ed_g, float* __restrict__ ed2_g)
{
    __shared__ float Xl[32][132];
    __shared__ float Wt[128][68];

    const int bid = blockIdx.x;
    const int t   = threadIdx.x;         // 0..255

    if (bid >= 512) {
        // ---------------- pack: one A row -> 64 bit-words ----------------
        const int row  = bid - 512;
        const int lane = t & 63;
        const int wv   = t >> 6;
        const int* arow = A + (size_t)row * NN;
        #pragma unroll 4
        for (int c = 0; c < 16; ++c) {
            const int col = c * 256 + wv * 64 + lane;
            unsigned long long m =
                __ballot(__builtin_nontemporal_load(&arow[col]) > 0);
            if (lane == 0) Abits[(size_t)row * 64 + c * 4 + wv] = m;
        }
        return;
    }

    // ---------------- prep: H = X@W[h]^T + b ----------------
    const int rb = bid & 127;
    const int h  = bid >> 7;
    const int n0 = rb * 32;

    for (int g = t; g < 32 * 32; g += 256) {
        int row = g >> 5, c4 = g & 31;
        float4 v = *(const float4*)&X[(size_t)(n0 + row) * FIN + c4 * 4];
        *(float4*)&Xl[row][c4 * 4] = v;
    }
    for (int g = t; g < 64 * 32; g += 256) {
        int o = g >> 5, c4 = g & 31;
        float4 v = *(const float4*)&W[((size_t)h * FOUT + o) * FIN + c4 * 4];
        Wt[c4 * 4 + 0][o] = v.x; Wt[c4 * 4 + 1][o] = v.y;
        Wt[c4 * 4 + 2][o] = v.z; Wt[c4 * 4 + 3][o] = v.w;
    }
    __syncthreads();

    const int rg = t >> 4;               // rows rg*2 .. rg*2+1
    const int og = t & 15;               // cols og*4 .. og*4+3
    float acc[2][4] = {};

    #pragma unroll 4
    for (int f4 = 0; f4 < 32; ++f4) {
        float xv[2][4], wv[4][4];
        #pragma unroll
        for (int i = 0; i < 2; ++i) {
            float4 tmp = *(const float4*)&Xl[rg * 2 + i][f4 * 4];
            xv[i][0] = tmp.x; xv[i][1] = tmp.y; xv[i][2] = tmp.z; xv[i][3] = tmp.w;
        }
        #pragma unroll
        for (int k = 0; k < 4; ++k) {
            float4 tmp = *(const float4*)&Wt[f4 * 4 + k][og * 4];
            wv[k][0] = tmp.x; wv[k][1] = tmp.y; wv[k][2] = tmp.z; wv[k][3] = tmp.w;
        }
        #pragma unroll
        for (int i = 0; i < 2; ++i)
            #pragma unroll
            for (int k = 0; k < 4; ++k)
                #pragma unroll
                for (int jj = 0; jj < 4; ++jj)
                    acc[i][jj] = fmaf(xv[i][k], wv[k][jj], acc[i][jj]);
    }

    float bb[4], as_[4], ad_[4];
    #pragma unroll
    for (int jj = 0; jj < 4; ++jj) {
        bb[jj]  = b[h * FOUT + og * 4 + jj];
        as_[jj] = att[h * 2 * FOUT + og * 4 + jj];
        ad_[jj] = att[h * 2 * FOUT + FOUT + og * 4 + jj];
    }
    #pragma unroll
    for (int i = 0; i < 2; ++i)
        #pragma unroll
        for (int jj = 0; jj < 4; ++jj)
            acc[i][jj] += bb[jj];

    float sp[2] = {0.f, 0.f}, dp[2] = {0.f, 0.f};
    #pragma unroll
    for (int i = 0; i < 2; ++i)
        #pragma unroll
        for (int jj = 0; jj < 4; ++jj) {
            sp[i] = fmaf(acc[i][jj], as_[jj], sp[i]);
            dp[i] = fmaf(acc[i][jj], ad_[jj], dp[i]);
        }
    #pragma unroll
    for (int off = 1; off < 16; off <<= 1) {
        #pragma unroll
        for (int i = 0; i < 2; ++i) {
            sp[i] += __shfl_xor(sp[i], off);
            dp[i] += __shfl_xor(dp[i], off);
        }
    }
    if (og == 0) {
        #pragma unroll
        for (int i = 0; i < 2; ++i) {
            int nn = n0 + rg * 2 + i;
            s_out[h * NN + nn]  = sp[i];
            d_out[h * NN + nn]  = dp[i];
            es_g [h * NN + nn]  = __expf(sp[i]);
            es2_g[h * NN + nn]  = __expf(0.01f * sp[i]);
            ed_g [h * NN + nn]  = __expf(dp[i]);
            ed2_g[h * NN + nn]  = __expf(0.01f * dp[i]);
        }
    }

    #pragma unroll
    for (int i = 0; i < 2; ++i) {
        float4 v = make_float4(acc[i][0], acc[i][1], acc[i][2], acc[i][3]);
        *(float4*)&Hrow[((size_t)h * NN + n0 + rg * 2 + i) * FOUT + og * 4] = v;
    }
    #pragma unroll
    for (int jj = 0; jj < 4; ++jj) {
        int o = og * 4 + jj;
        ushort2 p;
        p.x = f32_bf16(acc[0][jj]);
        p.y = f32_bf16(acc[1][jj]);
        *(ushort2*)&HbfT[((size_t)h * FOUT + o) * NN + n0 + rg * 2] = p;
    }
}

// ---------------- Kernel 2: masked softmax-aggregate ------------------------
// 1D grid 1024 x 512 thr (8 waves), XCD-clustered: grp=id&31 -> h=grp>>3,
// cg=grp&7 (id%8==cg); bx=id>>5 (128-row tiles).
// Block: 1 head x 128 rows x 512 cols; 2 chunks of 256 cols (8 steps/chunk),
// single-buffered LDS, 2 barriers per chunk (4 total).
__global__ __launch_bounds__(512, 8) void gat_main(
    const unsigned* __restrict__ Abits, const unsigned short* __restrict__ HbfT,
    const float* __restrict__ es_g, const float* __restrict__ es2_g,
    const float* __restrict__ ed_g, const float* __restrict__ ed2_g,
    float* __restrict__ Hpart, float* __restrict__ lpartP)
{
    const int id  = blockIdx.x;          // 0..1023
    const int grp = id & 31;             // XCD-clustered (id%8 == cg)
    const int h   = grp >> 3;            // head
    const int cg  = grp & 7;             // col slice: [cg*512, +512)
    const int bx  = id >> 5;             // 0..31 row tile (128 rows)
    const int n0  = bx * 128;
    const int tid  = threadIdx.x;        // 0..511
    const int w    = tid >> 6;           // wave 0..7 -> rows w*16..+16
    const int lane = tid & 63;
    const int r    = lane & 15;          // A row within subtile / C col
    const int q    = lane >> 4;          // quad
    const int qs   = q * 8;

    __shared__ unsigned short Hlds[64][256];     // 32 KB, XOR-swizzled 16B blocks
    __shared__ unsigned bits_lds[128 * 9];       // 4.6 KB (stride 9)

    const int n = n0 + w * 16 + r;
    const float es  = es_g [h * NN + n];
    const float es2 = es2_g[h * NN + n];
    const int bits_base = (w * 16 + r) * 9;

    bf16x8 ones;
    #pragma unroll
    for (int i = 0; i < 8; ++i) ones[i] = (short)0x3F80;   // bf16 1.0

    f32x4 acc0 = {0,0,0,0}, acc1 = {0,0,0,0}, acc2 = {0,0,0,0},
          acc3 = {0,0,0,0}, accl = {0,0,0,0};

    const unsigned short* hbase = HbfT + (size_t)h * FOUT * NN;

    for (int ch = 0; ch < 2; ++ch) {
        const int c0 = cg * 512 + ch * 256;
        __syncthreads();                 // previous chunk fully consumed

        // ---- stage H chunk: 64 x 256 -> 2048 16B-blocks, swizzled ----
        #pragma unroll
        for (int it = 0; it < 4; ++it) {
            int flat = it * 512 + tid;           // 0..2047
            int o    = flat >> 5;                // 0..63
            int c16  = flat & 31;
            int blk  = c16 ^ (o & 31);
            *(bf16x8*)&Hlds[o][blk * 8] =
                *(const bf16x8*)&hbase[(size_t)o * NN + c0 + c16 * 8];
        }
        // ---- stage adjacency bits: 128 rows x 8 u32 ----
        #pragma unroll
        for (int it = 0; it < 2; ++it) {
            int flat = it * 512 + tid;           // 0..1023
            int row = flat >> 3, wd = flat & 7;
            bits_lds[row * 9 + wd] = Abits[(size_t)(n0 + row) * 128 + (c0 >> 5) + wd];
        }
        __syncthreads();

        const float* edh  = ed_g  + h * NN + c0;
        const float* ed2h = ed2_g + h * NN + c0;

        #pragma unroll
        for (int step = 0; step < 8; ++step) {
            const unsigned bits8 = bits_lds[bits_base + step] >> qs;
            const int mk = step * 32 + qs;

            const float4 e0 = *(const float4*)&edh [mk];
            const float4 e1 = *(const float4*)&edh [mk + 4];
            const float4 g0 = *(const float4*)&ed2h[mk];
            const float4 g1 = *(const float4*)&ed2h[mk + 4];
            const float edv [8] = {e0.x, e0.y, e0.z, e0.w, e1.x, e1.y, e1.z, e1.w};
            const float ed2v[8] = {g0.x, g0.y, g0.z, g0.w, g1.x, g1.y, g1.z, g1.w};

            u32x4 afu;
            #pragma unroll
            for (int p = 0; p < 4; ++p) {
                const int j0 = 2 * p, j1 = 2 * p + 1;
                float wa = (bits8 & (1u << j0))
                         ? fmaxf(es * edv[j0], es2 * ed2v[j0]) : 0.0f;
                float wb = (bits8 & (1u << j1))
                         ? fmaxf(es * edv[j1], es2 * ed2v[j1]) : 0.0f;
                __hip_bfloat162 pk = __float22bfloat162_rn(make_float2(wa, wb));
                unsigned u;
                __builtin_memcpy(&u, &pk, sizeof(u));   // v_cvt_pk path
                afu[p] = u;
            }
            const bf16x8 af = __builtin_bit_cast(bf16x8, afu);

            // B fragments from swizzled LDS; rows r,r+16,r+32,r+48:
            // (row&31) = r, r+16, r, r+16
            const int mb   = step * 4 + q;       // 16B-block index, 0..31
            const int mbx0 = mb ^ r;
            const int mbx1 = mb ^ (r + 16);
            const bf16x8 b0 = *(const bf16x8*)&Hlds[r     ][mbx0 * 8];
            const bf16x8 b1 = *(const bf16x8*)&Hlds[r + 16][mbx1 * 8];
            const bf16x8 b2 = *(const bf16x8*)&Hlds[r + 32][mbx0 * 8];
            const bf16x8 b3 = *(const bf16x8*)&Hlds[r + 48][mbx1 * 8];

            acc0 = __builtin_amdgcn_mfma_f32_16x16x32_bf16(af, b0,   acc0, 0, 0, 0);
            acc1 = __builtin_amdgcn_mfma_f32_16x16x32_bf16(af, b1,   acc1, 0, 0, 0);
            acc2 = __builtin_amdgcn_mfma_f32_16x16x32_bf16(af, b2,   acc2, 0, 0, 0);
            acc3 = __builtin_amdgcn_mfma_f32_16x16x32_bf16(af, b3,   acc3, 0, 0, 0);
            accl = __builtin_amdgcn_mfma_f32_16x16x32_bf16(af, ones, accl, 0, 0, 0);
        }
    }

    // ---- epilogue: regular cached stores (L2 merges) ----
    float* hb = Hpart + ((size_t)(cg * NH + h) * NN + n0 + w * 16) * FOUT;
    #pragma unroll
    for (int reg = 0; reg < 4; ++reg) {
        const int rr = q * 4 + reg;
        hb[rr * FOUT +  0 + r] = acc0[reg];
        hb[rr * FOUT + 16 + r] = acc1[reg];
        hb[rr * FOUT + 32 + r] = acc2[reg];
        hb[rr * FOUT + 48 + r] = acc3[reg];
    }
    if (r == 0) {                        // col-0 lanes hold the 512-col row-sums
        #pragma unroll
        for (int reg = 0; reg < 4; ++reg)
            lpartP[(size_t)(cg * NH + h) * NN + n0 + w * 16 + q * 4 + reg] = accl[reg];
    }
}

// ---------------- Kernel 3: finalize ----------------
// out[n][o] = sum_h (sum_cg Hpart + w_diag*Hrow) * 0.25/(sum_cg l + w_diag)
__global__ __launch_bounds__(256) void gat_fin(
    const float* __restrict__ Hpart, const float* __restrict__ Hrow,
    const float* __restrict__ lpartP, const float* __restrict__ s_g,
    const float* __restrict__ d_g, float* __restrict__ out)
{
    const int tid = threadIdx.x;
    const int rr  = tid >> 4;
    const int c4  = tid & 15;
    const int n   = blockIdx.x * 16 + rr;
    const int o   = c4 * 4;

    float4 res = make_float4(0.f, 0.f, 0.f, 0.f);
    #pragma unroll
    for (int h = 0; h < NH; ++h) {
        float l = 0.f;
        #pragma unroll
        for (int cg = 0; cg < 8; ++cg)
            l += lpartP[(size_t)(cg * NH + h) * NN + n];
        float tt = s_g[h * NN + n] + d_g[h * NN + n];
        float wd = __expf(fmaxf(tt, 0.01f * tt));
        float inv = 0.25f / (l + wd);

        f32x4 ha = {0.f, 0.f, 0.f, 0.f};
        #pragma unroll
        for (int cg = 0; cg < 8; ++cg) {
            f32x4 hp = __builtin_nontemporal_load(
                (const f32x4*)&Hpart[((size_t)(cg * NH + h) * NN + n) * FOUT + o]);
            ha += hp;
        }
        float4 hr = *(const float4*)&Hrow[((size_t)h * NN + n) * FOUT + o];

        res.x += (ha[0] + wd * hr.x) * inv;
        res.y += (ha[1] + wd * hr.y) * inv;
        res.z += (ha[2] + wd * hr.z) * inv;
        res.w += (ha[3] + wd * hr.w) * inv;
    }
    *(float4*)&out[(size_t)n * FOUT + o] = res;
}

extern "C" void kernel_launch(void* const* d_in, const int* in_sizes, int n_in,
                              void* d_out, int out_size, void* d_ws, size_t ws_size,
                              hipStream_t stream) {
    const float* X   = (const float*)d_in[0];
    const int*   A   = (const int*)  d_in[1];
    const float* W   = (const float*)d_in[2];
    const float* b   = (const float*)d_in[3];
    const float* att = (const float*)d_in[4];
    float* out = (float*)d_out;

    char* ws = (char*)d_ws;
    unsigned short* HbfT = (unsigned short*)ws;                    // 2 MB
    size_t off = (size_t)NH * FOUT * NN * 2;
    float* s_buf   = (float*)(ws + off);  off += (size_t)NH * NN * 4;
    float* d_buf   = (float*)(ws + off);  off += (size_t)NH * NN * 4;
    float* es_buf  = (float*)(ws + off);  off += (size_t)NH * NN * 4;
    float* es2_buf = (float*)(ws + off);  off += (size_t)NH * NN * 4;
    float* ed_buf  = (float*)(ws + off);  off += (size_t)NH * NN * 4;
    float* ed2_buf = (float*)(ws + off);  off += (size_t)NH * NN * 4;
    unsigned long long* Abits = (unsigned long long*)(ws + off);
    off += (size_t)NN * 64 * 8;                                         // 2 MB
    float* Hrow   = (float*)(ws + off);
    off += (size_t)NH * NN * FOUT * 4;                                  // 4 MB
    float* Hpart  = (float*)(ws + off);
    off += (size_t)8 * NH * NN * FOUT * 4;                              // 33.5 MB
    float* lpartP = (float*)(ws + off);
    off += (size_t)8 * NH * NN * 4;                                     // 512 KB

    gat_pp<<<512 + NN, 256, 0, stream>>>(X, W, b, att, A, Abits, HbfT, Hrow,
                                         s_buf, d_buf,
                                         es_buf, es2_buf, ed_buf, ed2_buf);
    gat_main<<<1024, 512, 0, stream>>>((const unsigned*)Abits, HbfT,
                                       es_buf, es2_buf, ed_buf, ed2_buf,
                                       Hpart, lpartP);
    gat_fin<<<256, 256, 0, stream>>>(Hpart, Hrow, lpartP, s_buf, d_buf, out);
}

// Round 14
// 168.579 us; speedup vs baseline: 1.2490x; 1.2490x over previous
//
#include <hip/hip_runtime.h>
#include <hip/hip_bf16.h>

// GAT layer: N=4096, F_IN=128, F_OUT=64, HEADS=4.
// R14: REVERT to R11 exactly — the best measured configuration (168 us).
//  - gat_main: 1024 blocks x 512 thr, XCD-clustered (id%8==cg), 1 head x
//    128 rows x 512 cols per block, 4 single-buffered 128-col chunks,
//    cached Hpart stores. 32 waves/CU.
//  - R12 lesson: reg-prefetch double-buffering regressed (WRITE +34 MB, occ 62%).
//  - R13 lesson: 256-col chunks regressed (FETCH 40->85 MB, L2 thrash);
//    pack+prep fusion regressed (shared worst-case LDS killed pack occupancy).
// Kernels: pack_bits -> gat_prep -> gat_main -> gat_fin.

#define NN 4096
#define FIN 128
#define FOUT 64
#define NH 4

typedef __attribute__((ext_vector_type(8))) short bf16x8;
typedef __attribute__((ext_vector_type(4))) float f32x4;
typedef __attribute__((ext_vector_type(4))) unsigned int u32x4;

__device__ __forceinline__ unsigned short f32_bf16(float f) {
    unsigned u = __builtin_bit_cast(unsigned, f);
    u += 0x7fffu + ((u >> 16) & 1u);          // round-to-nearest-even
    return (unsigned short)(u >> 16);
}

// ---------------- Kernel 0: pack A (int32 0/1) into bitmask ----------------
__global__ __launch_bounds__(256) void pack_bits(
    const int* __restrict__ A, unsigned long long* __restrict__ Abits)
{
    const int row  = blockIdx.x;
    const int lane = threadIdx.x & 63;
    const int wv   = threadIdx.x >> 6;
    const int* arow = A + (size_t)row * NN;
    #pragma unroll 4
    for (int c = 0; c < 16; ++c) {
        const int col = c * 256 + wv * 64 + lane;
        unsigned long long m = __ballot(__builtin_nontemporal_load(&arow[col]) > 0);
        if (lane == 0) Abits[(size_t)row * 64 + c * 4 + wv] = m;
    }
}

// ---------------- Kernel 1: prep ----------------
__global__ __launch_bounds__(256) void gat_prep(
    const float* __restrict__ X, const float* __restrict__ W,
    const float* __restrict__ b, const float* __restrict__ att,
    unsigned short* __restrict__ HbfT, float* __restrict__ Hrow,
    float* __restrict__ s_out, float* __restrict__ d_out,
    float* __restrict__ es_g, float* __restrict__ es2_g,
    float* __restrict__ ed_g, float* __restrict__ ed2_g)
{
    const int rb = blockIdx.x;           // 0..127
    const int h  = blockIdx.y;           // 0..3
    const int n0 = rb * 32;
    const int t  = threadIdx.x;          // 0..255

    __shared__ float Xl[32][132];
    __shared__ float Wt[128][68];

    for (int g = t; g < 32 * 32; g += 256) {
        int row = g >> 5, c4 = g & 31;
        float4 v = *(const float4*)&X[(size_t)(n0 + row) * FIN + c4 * 4];
        *(float4*)&Xl[row][c4 * 4] = v;
    }
    for (int g = t; g < 64 * 32; g += 256) {
        int o = g >> 5, c4 = g & 31;
        float4 v = *(const float4*)&W[((size_t)h * FOUT + o) * FIN + c4 * 4];
        Wt[c4 * 4 + 0][o] = v.x; Wt[c4 * 4 + 1][o] = v.y;
        Wt[c4 * 4 + 2][o] = v.z; Wt[c4 * 4 + 3][o] = v.w;
    }
    __syncthreads();

    const int rg = t >> 4;               // rows rg*2 .. rg*2+1
    const int og = t & 15;               // cols og*4 .. og*4+3
    float acc[2][4] = {};

    #pragma unroll 4
    for (int f4 = 0; f4 < 32; ++f4) {
        float xv[2][4], wv[4][4];
        #pragma unroll
        for (int i = 0; i < 2; ++i) {
            float4 tmp = *(const float4*)&Xl[rg * 2 + i][f4 * 4];
            xv[i][0] = tmp.x; xv[i][1] = tmp.y; xv[i][2] = tmp.z; xv[i][3] = tmp.w;
        }
        #pragma unroll
        for (int k = 0; k < 4; ++k) {
            float4 tmp = *(const float4*)&Wt[f4 * 4 + k][og * 4];
            wv[k][0] = tmp.x; wv[k][1] = tmp.y; wv[k][2] = tmp.z; wv[k][3] = tmp.w;
        }
        #pragma unroll
        for (int i = 0; i < 2; ++i)
            #pragma unroll
            for (int k = 0; k < 4; ++k)
                #pragma unroll
                for (int jj = 0; jj < 4; ++jj)
                    acc[i][jj] = fmaf(xv[i][k], wv[k][jj], acc[i][jj]);
    }

    float bb[4], as_[4], ad_[4];
    #pragma unroll
    for (int jj = 0; jj < 4; ++jj) {
        bb[jj]  = b[h * FOUT + og * 4 + jj];
        as_[jj] = att[h * 2 * FOUT + og * 4 + jj];
        ad_[jj] = att[h * 2 * FOUT + FOUT + og * 4 + jj];
    }
    #pragma unroll
    for (int i = 0; i < 2; ++i)
        #pragma unroll
        for (int jj = 0; jj < 4; ++jj)
            acc[i][jj] += bb[jj];

    float sp[2] = {0.f, 0.f}, dp[2] = {0.f, 0.f};
    #pragma unroll
    for (int i = 0; i < 2; ++i)
        #pragma unroll
        for (int jj = 0; jj < 4; ++jj) {
            sp[i] = fmaf(acc[i][jj], as_[jj], sp[i]);
            dp[i] = fmaf(acc[i][jj], ad_[jj], dp[i]);
        }
    #pragma unroll
    for (int off = 1; off < 16; off <<= 1) {
        #pragma unroll
        for (int i = 0; i < 2; ++i) {
            sp[i] += __shfl_xor(sp[i], off);
            dp[i] += __shfl_xor(dp[i], off);
        }
    }
    if (og == 0) {
        #pragma unroll
        for (int i = 0; i < 2; ++i) {
            int nn = n0 + rg * 2 + i;
            s_out[h * NN + nn]  = sp[i];
            d_out[h * NN + nn]  = dp[i];
            es_g [h * NN + nn]  = __expf(sp[i]);
            es2_g[h * NN + nn]  = __expf(0.01f * sp[i]);
            ed_g [h * NN + nn]  = __expf(dp[i]);
            ed2_g[h * NN + nn]  = __expf(0.01f * dp[i]);
        }
    }

    #pragma unroll
    for (int i = 0; i < 2; ++i) {
        float4 v = make_float4(acc[i][0], acc[i][1], acc[i][2], acc[i][3]);
        *(float4*)&Hrow[((size_t)h * NN + n0 + rg * 2 + i) * FOUT + og * 4] = v;
    }
    #pragma unroll
    for (int jj = 0; jj < 4; ++jj) {
        int o = og * 4 + jj;
        ushort2 p;
        p.x = f32_bf16(acc[0][jj]);
        p.y = f32_bf16(acc[1][jj]);
        *(ushort2*)&HbfT[((size_t)h * FOUT + o) * NN + n0 + rg * 2] = p;
    }
}

// ---------------- Kernel 2: masked softmax-aggregate ------------------------
// 1D grid 1024 x 512 thr (8 waves), XCD-clustered: grp=id&31 -> h=grp>>3,
// cg=grp&7 (id%8==cg); bx=id>>5 (0..31, 128-row tiles).
// Block: 1 head x 128 rows x 512 cols, 4 chunks of 128 cols.
__global__ __launch_bounds__(512, 8) void gat_main(
    const unsigned* __restrict__ Abits, const unsigned short* __restrict__ HbfT,
    const float* __restrict__ es_g, const float* __restrict__ es2_g,
    const float* __restrict__ ed_g, const float* __restrict__ ed2_g,
    float* __restrict__ Hpart, float* __restrict__ lpartP)
{
    const int id  = blockIdx.x;          // 0..1023
    const int grp = id & 31;             // XCD-clustered group (id%8 == cg)
    const int h   = grp >> 3;            // head
    const int cg  = grp & 7;             // col slice: [cg*512, +512)
    const int bx  = id >> 5;             // 0..31 row tile (128 rows)
    const int n0  = bx * 128;
    const int tid  = threadIdx.x;        // 0..511
    const int w    = tid >> 6;           // wave 0..7 -> rows w*16..+16
    const int lane = tid & 63;
    const int r    = lane & 15;          // A row within subtile / C col
    const int q    = lane >> 4;          // quad
    const int qs   = q * 8;

    __shared__ unsigned short Hlds[64][128];     // 16 KB, XOR-swizzled 16B blocks
    __shared__ unsigned bits_lds[128 * 5];       // 2.5 KB (stride 5)

    const int n = n0 + w * 16 + r;
    const float es  = es_g [h * NN + n];
    const float es2 = es2_g[h * NN + n];
    const int bits_base = (w * 16 + r) * 5;

    bf16x8 ones;
    #pragma unroll
    for (int i = 0; i < 8; ++i) ones[i] = (short)0x3F80;   // bf16 1.0

    f32x4 acc0 = {0,0,0,0}, acc1 = {0,0,0,0}, acc2 = {0,0,0,0},
          acc3 = {0,0,0,0}, accl = {0,0,0,0};

    for (int ch = 0; ch < 4; ++ch) {
        const int c0 = cg * 512 + ch * 128;
        __syncthreads();                 // previous chunk fully consumed

        // ---- stage H chunk: HbfT[h][o][c0..c0+128) -> Hlds[o][.], swizzled ----
        #pragma unroll
        for (int it = 0; it < 2; ++it) {
            int flat = it * 512 + tid;           // 0..1023 (16B blocks)
            int o    = flat >> 4;                // 0..63
            int c16  = flat & 15;
            int blk  = c16 ^ (o & 15);
            *(bf16x8*)&Hlds[o][blk * 8] =
                *(const bf16x8*)&HbfT[((size_t)h * FOUT + o) * NN + c0 + c16 * 8];
        }
        // ---- stage adjacency bits: 128 rows x 4 u32 for this chunk ----
        {
            int row = tid >> 2, wd = tid & 3;    // 512 threads cover 128x4
            bits_lds[row * 5 + wd] = Abits[(size_t)(n0 + row) * 128 + (c0 >> 5) + wd];
        }
        __syncthreads();

        const float* edh  = ed_g  + h * NN + c0;
        const float* ed2h = ed2_g + h * NN + c0;

        #pragma unroll
        for (int step = 0; step < 4; ++step) {
            const unsigned bits8 = bits_lds[bits_base + step] >> qs;
            const int mk = step * 32 + qs;

            const float4 e0 = *(const float4*)&edh [mk];
            const float4 e1 = *(const float4*)&edh [mk + 4];
            const float4 g0 = *(const float4*)&ed2h[mk];
            const float4 g1 = *(const float4*)&ed2h[mk + 4];
            const float edv [8] = {e0.x, e0.y, e0.z, e0.w, e1.x, e1.y, e1.z, e1.w};
            const float ed2v[8] = {g0.x, g0.y, g0.z, g0.w, g1.x, g1.y, g1.z, g1.w};

            u32x4 afu;
            #pragma unroll
            for (int p = 0; p < 4; ++p) {
                const int j0 = 2 * p, j1 = 2 * p + 1;
                float wa = (bits8 & (1u << j0))
                         ? fmaxf(es * edv[j0], es2 * ed2v[j0]) : 0.0f;
                float wb = (bits8 & (1u << j1))
                         ? fmaxf(es * edv[j1], es2 * ed2v[j1]) : 0.0f;
                __hip_bfloat162 pk = __float22bfloat162_rn(make_float2(wa, wb));
                unsigned u;
                __builtin_memcpy(&u, &pk, sizeof(u));   // v_cvt_pk path
                afu[p] = u;
            }
            const bf16x8 af = __builtin_bit_cast(bf16x8, afu);

            // B fragments from swizzled LDS ((r+16k)&15 == r for all four)
            const int mb = (step * 4 + q) ^ r;   // 16B-block index after swizzle
            const bf16x8 b0 = *(const bf16x8*)&Hlds[r     ][mb * 8];
            const bf16x8 b1 = *(const bf16x8*)&Hlds[r + 16][mb * 8];
            const bf16x8 b2 = *(const bf16x8*)&Hlds[r + 32][mb * 8];
            const bf16x8 b3 = *(const bf16x8*)&Hlds[r + 48][mb * 8];

            acc0 = __builtin_amdgcn_mfma_f32_16x16x32_bf16(af, b0,   acc0, 0, 0, 0);
            acc1 = __builtin_amdgcn_mfma_f32_16x16x32_bf16(af, b1,   acc1, 0, 0, 0);
            acc2 = __builtin_amdgcn_mfma_f32_16x16x32_bf16(af, b2,   acc2, 0, 0, 0);
            acc3 = __builtin_amdgcn_mfma_f32_16x16x32_bf16(af, b3,   acc3, 0, 0, 0);
            accl = __builtin_amdgcn_mfma_f32_16x16x32_bf16(af, ones, accl, 0, 0, 0);
        }
    }

    // ---- epilogue: regular cached stores (L2 merges 64B halves) ----
    float* hb = Hpart + ((size_t)(cg * NH + h) * NN + n0 + w * 16) * FOUT;
    #pragma unroll
    for (int reg = 0; reg < 4; ++reg) {
        const int rr = q * 4 + reg;
        hb[rr * FOUT +  0 + r] = acc0[reg];
        hb[rr * FOUT + 16 + r] = acc1[reg];
        hb[rr * FOUT + 32 + r] = acc2[reg];
        hb[rr * FOUT + 48 + r] = acc3[reg];
    }
    if (r == 0) {                        // col-0 lanes hold the 512-col row-sums
        #pragma unroll
        for (int reg = 0; reg < 4; ++reg)
            lpartP[(size_t)(cg * NH + h) * NN + n0 + w * 16 + q * 4 + reg] = accl[reg];
    }
}

// ---------------- Kernel 3: finalize ----------------
// out[n][o] = sum_h (sum_cg Hpart + w_diag*Hrow) * 0.25/(sum_cg l + w_diag)
__global__ __launch_bounds__(256) void gat_fin(
    const float* __restrict__ Hpart, const float* __restrict__ Hrow,
    const float* __restrict__ lpartP, const float* __restrict__ s_g,
    const float* __restrict__ d_g, float* __restrict__ out)
{
    const int tid = threadIdx.x;
    const int rr  = tid >> 4;
    const int c4  = tid & 15;
    const int n   = blockIdx.x * 16 + rr;
    const int o   = c4 * 4;

    float4 res = make_float4(0.f, 0.f, 0.f, 0.f);
    #pragma unroll
    for (int h = 0; h < NH; ++h) {
        float l = 0.f;
        #pragma unroll
        for (int cg = 0; cg < 8; ++cg)
            l += lpartP[(size_t)(cg * NH + h) * NN + n];
        float tt = s_g[h * NN + n] + d_g[h * NN + n];
        float wd = __expf(fmaxf(tt, 0.01f * tt));
        float inv = 0.25f / (l + wd);

        f32x4 ha = {0.f, 0.f, 0.f, 0.f};
        #pragma unroll
        for (int cg = 0; cg < 8; ++cg) {
            f32x4 hp = __builtin_nontemporal_load(
                (const f32x4*)&Hpart[((size_t)(cg * NH + h) * NN + n) * FOUT + o]);
            ha += hp;
        }
        float4 hr = *(const float4*)&Hrow[((size_t)h * NN + n) * FOUT + o];

        res.x += (ha[0] + wd * hr.x) * inv;
        res.y += (ha[1] + wd * hr.y) * inv;
        res.z += (ha[2] + wd * hr.z) * inv;
        res.w += (ha[3] + wd * hr.w) * inv;
    }
    *(float4*)&out[(size_t)n * FOUT + o] = res;
}

extern "C" void kernel_launch(void* const* d_in, const int* in_sizes, int n_in,
                              void* d_out, int out_size, void* d_ws, size_t ws_size,
                              hipStream_t stream) {
    const float* X   = (const float*)d_in[0];
    const int*   A   = (const int*)  d_in[1];
    const float* W   = (const float*)d_in[2];
    const float* b   = (const float*)d_in[3];
    const float* att = (const float*)d_in[4];
    float* out = (float*)d_out;

    char* ws = (char*)d_ws;
    unsigned short* HbfT = (unsigned short*)ws;                    // 2 MB
    size_t off = (size_t)NH * FOUT * NN * 2;
    float* s_buf   = (float*)(ws + off);  off += (size_t)NH * NN * 4;
    float* d_buf   = (float*)(ws + off);  off += (size_t)NH * NN * 4;
    float* es_buf  = (float*)(ws + off);  off += (size_t)NH * NN * 4;
    float* es2_buf = (float*)(ws + off);  off += (size_t)NH * NN * 4;
    float* ed_buf  = (float*)(ws + off);  off += (size_t)NH * NN * 4;
    float* ed2_buf = (float*)(ws + off);  off += (size_t)NH * NN * 4;
    unsigned long long* Abits = (unsigned long long*)(ws + off);
    off += (size_t)NN * 64 * 8;                                         // 2 MB
    float* Hrow   = (float*)(ws + off);
    off += (size_t)NH * NN * FOUT * 4;                                  // 4 MB
    float* Hpart  = (float*)(ws + off);
    off += (size_t)8 * NH * NN * FOUT * 4;                              // 33.5 MB
    float* lpartP = (float*)(ws + off);
    off += (size_t)8 * NH * NN * 4;                                     // 512 KB

    pack_bits<<<NN, 256, 0, stream>>>(A, Abits);
    gat_prep<<<dim3(128, 4), 256, 0, stream>>>(X, W, b, att, HbfT, Hrow,
                                               s_buf, d_buf,
                                               es_buf, es2_buf, ed_buf, ed2_buf);
    gat_main<<<1024, 512, 0, stream>>>((const unsigned*)Abits, HbfT,
                                       es_buf, es2_buf, ed_buf, ed2_buf,
                                       Hpart, lpartP);
    gat_fin<<<256, 256, 0, stream>>>(Hpart, Hrow, lpartP, s_buf, d_buf, out);
}